// Round 7
// baseline (803.937 us; speedup 1.0000x reference)
//
#include <hip/hip_runtime.h>
#include <hip/hip_cooperative_groups.h>
#include <stdint.h>
#include <stddef.h>

namespace cg = cooperative_groups;

// GraphSAGE-mean 2-layer pipeline on MI355X — round 7: ONE cooperative dispatch.
//   h   = relu(feat @ W_init + b_init)                      [200000,128] bf16
//   l0: hn = segment_mean(h[src0], dst0); h1 = relu(h[:50000]@Ws + hn@Wn + b)
//   l1: hn = segment_mean(h1[src1], dst1); out = h1[:10000]@Ws + hn@Wn + b  f32
//
// R1..R6 evidence: totals 326/313/306/309 us across wildly different kernel
// structures while the sum of measured/modeled kernels is ~160-180 us -> the
// floor is ~7 inter-dispatch gaps x ~15-20 us, not the kernels. R7 fuses the
// whole pipeline into one hipLaunchCooperativeKernel with grid.sync() phases:
//   P0 prep Wf + zero cnt
//   P1 place (wave 0 of each block, dst-partitioned) || fc_init (waves 1-3)
//   P2 agg0   P3 sage0   P4 agg1   P5 sage1
// Per-phase bodies are the R6-verified structures (one-shot strips, wave-per-dst
// gather). 64 KB LDS (two W-fragment planes) -> exactly 2 blocks/CU, grid 512.

#define DIM 128
constexpr int N_SRC0 = 200000;
constexpr int N_DST0 = 50000;
constexpr int N_DST1 = 10000;
constexpr int E0 = 800000;
constexpr int E1 = 160000;
constexpr int MAXDEG = 64;   // Poisson(16): max deg over 50k bins ~45 — safe

typedef __attribute__((ext_vector_type(8))) short bf16x8;   // 8 bf16 = 4 VGPRs
typedef __attribute__((ext_vector_type(4))) float f32x4;    // MFMA C/D

__device__ __forceinline__ uint16_t f2bf(float f) {
  union { float f; uint32_t u; } v; v.f = f;
  return (uint16_t)((v.u + 0x7FFFu + ((v.u >> 16) & 1u)) >> 16);  // RNE
}
__device__ __forceinline__ float bf2f(uint16_t h) {
  union { uint32_t u; float f; } v; v.u = ((uint32_t)h) << 16;
  return v.f;
}

// ---- fc strip: 16 rows of relu(feat @ W + b) -> h (bf16). W frags in LDS. ----
__device__ __forceinline__ void fc_strip(int s, const float* feat,
                                         const uint16_t* wl, const float* bv,
                                         uint16_t* hout, int lane) {
  const int q = lane >> 4, m16 = lane & 15;
  const float* ap = feat + (size_t)(s * 16 + m16) * DIM + q * 8;
  float4 X[8];
#pragma unroll
  for (int kc = 0; kc < 4; kc++) {
    X[2 * kc]     = *(const float4*)(ap + kc * 32);
    X[2 * kc + 1] = *(const float4*)(ap + kc * 32 + 4);
  }
  f32x4 acc[8];
#pragma unroll
  for (int nt = 0; nt < 8; nt++) acc[nt] = (f32x4){0.f, 0.f, 0.f, 0.f};
#pragma unroll
  for (int kc = 0; kc < 4; kc++) {
    float xs[8] = {X[2 * kc].x, X[2 * kc].y, X[2 * kc].z, X[2 * kc].w,
                   X[2 * kc + 1].x, X[2 * kc + 1].y, X[2 * kc + 1].z, X[2 * kc + 1].w};
    bf16x8 a;
#pragma unroll
    for (int j = 0; j < 8; j++) a[j] = (short)f2bf(xs[j]);
#pragma unroll
    for (int nt = 0; nt < 8; nt++) {
      bf16x8 wv = *(const bf16x8*)&wl[((kc * 8 + nt) * 64 + lane) * 8];
      acc[nt] = __builtin_amdgcn_mfma_f32_16x16x32_bf16(a, wv, acc[nt], 0, 0, 0);
    }
  }
  int m0 = s * 16;
#pragma unroll
  for (int nt = 0; nt < 8; nt++)
#pragma unroll
    for (int r = 0; r < 4; r++) {
      float v = fmaxf(acc[nt][r] + bv[nt], 0.f);
      hout[(size_t)(m0 + q * 4 + r) * DIM + nt * 16 + m16] = f2bf(v);
    }
}

// ---- agg: one dst per wave; lane owns 2 cols; mean -> bf16. ----
__device__ __forceinline__ void agg_dst(int d, const int* eslot, const int* deg,
                                        const uint16_t* hsrc, uint16_t* hout,
                                        int lane) {
  const int* sl = eslot + (size_t)d * MAXDEG;
  int dg = deg[d];
  int dgc = dg < MAXDEG ? dg : MAXDEG;
  float a0 = 0.f, a1 = 0.f;
  int e = 0;
  for (; e + 4 <= dgc; e += 4) {
    int s0 = sl[e], s1 = sl[e + 1], s2 = sl[e + 2], s3 = sl[e + 3];
    uint32_t p0 = *(const uint32_t*)(hsrc + (size_t)s0 * DIM + lane * 2);
    uint32_t p1 = *(const uint32_t*)(hsrc + (size_t)s1 * DIM + lane * 2);
    uint32_t p2 = *(const uint32_t*)(hsrc + (size_t)s2 * DIM + lane * 2);
    uint32_t p3 = *(const uint32_t*)(hsrc + (size_t)s3 * DIM + lane * 2);
    a0 += bf2f((uint16_t)p0) + bf2f((uint16_t)p1) + bf2f((uint16_t)p2) + bf2f((uint16_t)p3);
    a1 += bf2f((uint16_t)(p0 >> 16)) + bf2f((uint16_t)(p1 >> 16)) +
          bf2f((uint16_t)(p2 >> 16)) + bf2f((uint16_t)(p3 >> 16));
  }
  for (; e < dgc; e++) {
    uint32_t p = *(const uint32_t*)(hsrc + (size_t)sl[e] * DIM + lane * 2);
    a0 += bf2f((uint16_t)p);
    a1 += bf2f((uint16_t)(p >> 16));
  }
  float inv = 1.f / fmaxf((float)dg, 1.f);
  uint32_t o = (uint32_t)f2bf(a0 * inv) | ((uint32_t)f2bf(a1 * inv) << 16);
  *(uint32_t*)(hout + (size_t)d * DIM + lane * 2) = o;
}

// ---- sage strip: 16 rows of act(hself@Ws + hneigh@Wn + b). W frags in LDS. ----
template <bool ACT, bool OUT_BF16>
__device__ __forceinline__ void sage_strip(int s, const uint16_t* hself,
                                           const uint16_t* hneigh,
                                           const uint16_t* wS, const uint16_t* wN,
                                           const float* bv, void* outp, int lane) {
  const int q = lane >> 4, m16 = lane & 15;
  size_t ro = (size_t)(s * 16 + m16) * DIM + q * 8;
  bf16x8 XS[4], XN[4];
#pragma unroll
  for (int kc = 0; kc < 4; kc++) {
    XS[kc] = *(const bf16x8*)(hself + ro + kc * 32);
    XN[kc] = *(const bf16x8*)(hneigh + ro + kc * 32);
  }
  f32x4 acc[8];
#pragma unroll
  for (int nt = 0; nt < 8; nt++) acc[nt] = (f32x4){0.f, 0.f, 0.f, 0.f};
#pragma unroll
  for (int kc = 0; kc < 4; kc++) {
#pragma unroll
    for (int nt = 0; nt < 8; nt++) {
      size_t fo = (size_t)((kc * 8 + nt) * 64 + lane) * 8;
      bf16x8 ws = *(const bf16x8*)&wS[fo];
      bf16x8 wn = *(const bf16x8*)&wN[fo];
      acc[nt] = __builtin_amdgcn_mfma_f32_16x16x32_bf16(XS[kc], ws, acc[nt], 0, 0, 0);
      acc[nt] = __builtin_amdgcn_mfma_f32_16x16x32_bf16(XN[kc], wn, acc[nt], 0, 0, 0);
    }
  }
  int m0 = s * 16;
#pragma unroll
  for (int nt = 0; nt < 8; nt++)
#pragma unroll
    for (int r = 0; r < 4; r++) {
      float v = acc[nt][r] + bv[nt];
      if (ACT) v = fmaxf(v, 0.f);
      size_t o = (size_t)(m0 + q * 4 + r) * DIM + nt * 16 + m16;
      if (OUT_BF16) ((uint16_t*)outp)[o] = f2bf(v);
      else          ((float*)outp)[o] = v;
    }
}

// ---------------------------------------------------------------------------
__global__ void __launch_bounds__(256, 2) mega_kernel(
    const float* __restrict__ feat,
    const int* __restrict__ src0, const int* __restrict__ dst0,
    const int* __restrict__ src1, const int* __restrict__ dst1,
    const float* __restrict__ W_init, const float* __restrict__ b_init,
    const float* __restrict__ W_self, const float* __restrict__ b_self,
    const float* __restrict__ W_neigh, const float* __restrict__ b_neigh,
    uint16_t* __restrict__ h, uint16_t* __restrict__ h1, uint16_t* __restrict__ hn,
    int* cnt0, int* cnt1,
    int* __restrict__ eslot0, int* __restrict__ eslot1,
    uint16_t* __restrict__ Wf, float* __restrict__ outp) {
  __shared__ uint16_t wA[16384];   // 32 KB
  __shared__ uint16_t wB[16384];   // 32 KB  -> 64 KB total, 2 blocks/CU
  cg::grid_group grid = cg::this_grid();

  const int tid = threadIdx.x;
  const int w = tid >> 6, lane = tid & 63;
  const int m16 = lane & 15;
  const int gw = blockIdx.x * 4 + w;
  const int nwav = gridDim.x * 4;
  const int nthr = gridDim.x * 256;
  const int gid = blockIdx.x * 256 + tid;

  // ---- P0: build Wf (3 matrices, MFMA-frag order bf16) + zero counters ----
  for (int i = gid; i < 3 * 16384; i += nthr) {
    int m = i >> 14, idx = i & 16383;
    const float* W = m == 0 ? W_init : (m == 1 ? W_self : W_neigh);
    int j = idx & 7, ln = (idx >> 3) & 63, nt = (idx >> 9) & 7, kc = idx >> 12;
    Wf[i] = f2bf(W[(kc * 32 + (ln >> 4) * 8 + j) * DIM + nt * 16 + (ln & 15)]);
  }
  for (int z = gid; z < N_DST0; z += nthr) cnt0[z] = 0;
  for (int z = gid; z < N_DST1; z += nthr) cnt1[z] = 0;
  grid.sync();

  // ---- P1: stage wA=WfI; wave 0 -> place (both layers), waves 1-3 -> fc ----
  {
    const uint4* g = (const uint4*)Wf;
    uint4* sdst = (uint4*)wA;
    for (int i = tid; i < 2048; i += 256) sdst[i] = g[i];
  }
  __syncthreads();
  if (w == 0) {
    // dst-partitioned slot scatter: partition = blockIdx&7 (XCD heuristic);
    // each partition scans all edges (L3-absorbed) but writes only its own
    // dst slice -> slot lines fill in one XCD's L2 before eviction.
    int part = blockIdx.x & 7;
    int bpp  = gridDim.x >> 3;
    int bidx = blockIdx.x >> 3;
    const int4* s04 = (const int4*)src0;
    const int4* d04 = (const int4*)dst0;
    const int4* s14 = (const int4*)src1;
    const int4* d14 = (const int4*)dst1;
    int lo = part * (N_DST0 / 8), hi = lo + (N_DST0 / 8);
    for (int i = bidx * 64 + lane; i < E0 / 4; i += bpp * 64) {
      int4 d = d04[i]; int4 s = s04[i];
      if (d.x >= lo && d.x < hi) { int p = atomicAdd(&cnt0[d.x], 1); if (p < MAXDEG) eslot0[(size_t)d.x * MAXDEG + p] = s.x; }
      if (d.y >= lo && d.y < hi) { int p = atomicAdd(&cnt0[d.y], 1); if (p < MAXDEG) eslot0[(size_t)d.y * MAXDEG + p] = s.y; }
      if (d.z >= lo && d.z < hi) { int p = atomicAdd(&cnt0[d.z], 1); if (p < MAXDEG) eslot0[(size_t)d.z * MAXDEG + p] = s.z; }
      if (d.w >= lo && d.w < hi) { int p = atomicAdd(&cnt0[d.w], 1); if (p < MAXDEG) eslot0[(size_t)d.w * MAXDEG + p] = s.w; }
    }
    int lo1 = part * (N_DST1 / 8), hi1 = lo1 + (N_DST1 / 8);
    for (int i = bidx * 64 + lane; i < E1 / 4; i += bpp * 64) {
      int4 d = d14[i]; int4 s = s14[i];
      if (d.x >= lo1 && d.x < hi1) { int p = atomicAdd(&cnt1[d.x], 1); if (p < MAXDEG) eslot1[(size_t)d.x * MAXDEG + p] = s.x; }
      if (d.y >= lo1 && d.y < hi1) { int p = atomicAdd(&cnt1[d.y], 1); if (p < MAXDEG) eslot1[(size_t)d.y * MAXDEG + p] = s.y; }
      if (d.z >= lo1 && d.z < hi1) { int p = atomicAdd(&cnt1[d.z], 1); if (p < MAXDEG) eslot1[(size_t)d.z * MAXDEG + p] = s.z; }
      if (d.w >= lo1 && d.w < hi1) { int p = atomicAdd(&cnt1[d.w], 1); if (p < MAXDEG) eslot1[(size_t)d.w * MAXDEG + p] = s.w; }
    }
  } else {
    float bv[8];
#pragma unroll
    for (int nt = 0; nt < 8; nt++) bv[nt] = b_init[nt * 16 + m16];
    for (int s = blockIdx.x * 3 + (w - 1); s < N_SRC0 / 16; s += gridDim.x * 3)
      fc_strip(s, feat, wA, bv, h, lane);
  }
  grid.sync();

  // ---- P2: agg0 (wave-per-dst, grid-strided) ----
  for (int d = gw; d < N_DST0; d += nwav) agg_dst(d, eslot0, cnt0, h, hn, lane);
  grid.sync();

  // ---- P3: restage wA=WfS, wB=WfN; sage0 ----
  {
    const uint4* gS = (const uint4*)(Wf + 16384);
    const uint4* gN = (const uint4*)(Wf + 32768);
    uint4* sA = (uint4*)wA;
    uint4* sB = (uint4*)wB;
    for (int i = tid; i < 2048; i += 256) { sA[i] = gS[i]; sB[i] = gN[i]; }
  }
  __syncthreads();
  {
    float bv[8];
#pragma unroll
    for (int nt = 0; nt < 8; nt++)
      bv[nt] = b_self[nt * 16 + m16] + b_neigh[nt * 16 + m16];
    for (int s = gw; s < N_DST0 / 16; s += nwav)
      sage_strip<true, true>(s, h, hn, wA, wB, bv, h1, lane);
    grid.sync();

    // ---- P4: agg1 ----
    for (int d = gw; d < N_DST1; d += nwav) agg_dst(d, eslot1, cnt1, h1, hn, lane);
    grid.sync();

    // ---- P5: sage1 (W planes unchanged since P3) ----
    for (int s = gw; s < N_DST1 / 16; s += nwav)
      sage_strip<false, false>(s, h1, hn, wA, wB, bv, outp, lane);
  }
}

// ---------------------------------------------------------------------------
// Workspace layout (bytes), total ~92.7 MB (ws_size ~409.6 MB):
//   h      @ 0           200000*128 bf16 = 51,200,000
//   h1     @ 51,200,000   50000*128 bf16 = 12,800,000
//   cnt0   @ 64,000,000   50000 int      =    200,000
//   cnt1   @ 64,200,000   10000 int      =     40,000
//   eslot0 @ 64,240,000   50000*64 int   = 12,800,000
//   eslot1 @ 77,040,000   10000*64 int   =  2,560,000
//   hn     @ 79,600,000   50000*128 bf16 = 12,800,000
//   Wf     @ 92,400,000   3*16384 bf16   =     98,304
// ---------------------------------------------------------------------------
extern "C" void kernel_launch(void* const* d_in, const int* in_sizes, int n_in,
                              void* d_out, int out_size, void* d_ws, size_t ws_size,
                              hipStream_t stream) {
  const float* feat   = (const float*)d_in[0];
  const int* src0     = (const int*)d_in[1];
  const int* dst0     = (const int*)d_in[2];
  const int* src1     = (const int*)d_in[3];
  const int* dst1     = (const int*)d_in[4];
  const float* W_init = (const float*)d_in[5];
  const float* b_init = (const float*)d_in[6];
  const float* W_self = (const float*)d_in[7];
  const float* b_self = (const float*)d_in[8];
  const float* W_neigh= (const float*)d_in[9];
  const float* b_neigh= (const float*)d_in[10];

  char* ws = (char*)d_ws;
  uint16_t* h     = (uint16_t*)(ws + 0);
  uint16_t* h1    = (uint16_t*)(ws + 51200000);
  int*      cnt0  = (int*)(ws + 64000000);
  int*      cnt1  = (int*)(ws + 64200000);
  int*      eslot0= (int*)(ws + 64240000);
  int*      eslot1= (int*)(ws + 77040000);
  uint16_t* hn    = (uint16_t*)(ws + 79600000);
  uint16_t* Wf    = (uint16_t*)(ws + 92400000);
  float*    outp  = (float*)d_out;

  // grid must be co-resident (2 blocks/CU at 64 KB LDS -> 512) and div by 8
  // (place partitioning). Query occupancy defensively; clamp to 512.
  int maxb = 2;
  hipOccupancyMaxActiveBlocksPerMultiprocessor(&maxb, (const void*)mega_kernel, 256, 0);
  int grid = maxb * 256;
  if (grid > 512) grid = 512;
  grid &= ~7;
  if (grid < 8) grid = 8;

  void* args[] = {
    (void*)&feat, (void*)&src0, (void*)&dst0, (void*)&src1, (void*)&dst1,
    (void*)&W_init, (void*)&b_init, (void*)&W_self, (void*)&b_self,
    (void*)&W_neigh, (void*)&b_neigh,
    (void*)&h, (void*)&h1, (void*)&hn, (void*)&cnt0, (void*)&cnt1,
    (void*)&eslot0, (void*)&eslot1, (void*)&Wf, (void*)&outp,
  };
  hipLaunchCooperativeKernel((const void*)mega_kernel, dim3(grid), dim3(256),
                             args, 0, stream);
}

// Round 8
// 324.744 us; speedup vs baseline: 2.4756x; 2.4756x over previous
//
#include <hip/hip_runtime.h>
#include <stdint.h>
#include <stddef.h>

// GraphSAGE-mean 2-layer pipeline on MI355X — round 8.
//   h   = relu(feat @ W_init + b_init)                      [200000,128] bf16
//   l0: hn = segment_mean(h[src0], dst0); h1 = relu(h[:50000]@Ws + hn@Wn + b)
//   l1: hn = segment_mean(h1[src1], dst1); out = h1[:10000]@Ws + hn@Wn + b  f32
//
// R7 lessons: cooperative launch costs ~176 us (dur 804 vs kernel 628) and
// capping the grid at 512 blocks starves latency-chain phases of waves
// (5-10x slowdown). R8 reverts to the R4/R6 split-kernel structure (best 306)
// with two nodes removed:
//  - place folded into the fc dispatch as independent blocks (0-255 = place,
//    256+ = fc strips). place's wall time hides under fc.
//  - 6 dispatches: setup -> fcplace -> agg0 -> sage0 -> agg1 -> sage1.
// All phase bodies are the R6-verified max-wave one-shot structures.

#define DIM 128
constexpr int N_SRC0 = 200000;
constexpr int N_DST0 = 50000;
constexpr int N_DST1 = 10000;
constexpr int E0 = 800000;
constexpr int E1 = 160000;
constexpr int MAXDEG = 64;   // Poisson(16): max deg over 50k bins ~45 — safe
constexpr int PLACE_BLOCKS = 256;   // must be divisible by 8

typedef __attribute__((ext_vector_type(8))) short bf16x8;   // 8 bf16 = 4 VGPRs
typedef __attribute__((ext_vector_type(4))) float f32x4;    // MFMA C/D

__device__ __forceinline__ uint16_t f2bf(float f) {
  union { float f; uint32_t u; } v; v.f = f;
  return (uint16_t)((v.u + 0x7FFFu + ((v.u >> 16) & 1u)) >> 16);  // RNE
}
__device__ __forceinline__ float bf2f(uint16_t h) {
  union { uint32_t u; float f; } v; v.u = ((uint32_t)h) << 16;
  return v.f;
}

// ---------------------------------------------------------------------------
// setup: Wf frags for 3 matrices (MFMA-frag-order bf16) + zero both counters.
// ---------------------------------------------------------------------------
__global__ __launch_bounds__(512) void setup_kernel(
    const float* __restrict__ W0, const float* __restrict__ W1,
    const float* __restrict__ W2, uint16_t* __restrict__ Wf,
    int* __restrict__ cnt, int ncnt) {
  int gid = blockIdx.x * 512 + threadIdx.x;
  if (gid < 3 * 16384) {
    int m = gid >> 14, idx = gid & 16383;
    const float* W = m == 0 ? W0 : (m == 1 ? W1 : W2);
    int j = idx & 7, lane = (idx >> 3) & 63, nt = (idx >> 9) & 7, kc = idx >> 12;
    Wf[gid] = f2bf(W[(kc * 32 + (lane >> 4) * 8 + j) * DIM + nt * 16 + (lane & 15)]);
  }
  int z = gid - 3 * 16384;
  if (z >= 0 && z < ncnt) cnt[z] = 0;
}

// ---------------------------------------------------------------------------
// fcplace: blocks 0..255 -> dst-partitioned slot scatter (both layers);
//          blocks 256+   -> fc one-shot strips (one 16-row strip per wave).
// ---------------------------------------------------------------------------
__global__ __launch_bounds__(256) void fcplace_kernel(
    const float* __restrict__ feat, const uint16_t* __restrict__ Wf,
    const float* __restrict__ bias, uint16_t* __restrict__ hout,
    const int* __restrict__ src0, const int* __restrict__ dst0,
    const int* __restrict__ src1, const int* __restrict__ dst1,
    int* __restrict__ cnt0, int* __restrict__ cnt1,
    int* __restrict__ eslot0, int* __restrict__ eslot1) {
  if (blockIdx.x < PLACE_BLOCKS) {
    // ---- place role: partition = blockIdx&7 (XCD heuristic); each partition
    // scans all edges (L3-absorbed) but writes only its own dst slice so slot
    // lines fill in one XCD's L2 before eviction. ----
    int part = blockIdx.x & 7;
    int bpp  = PLACE_BLOCKS >> 3;
    int bidx = blockIdx.x >> 3;
    const int4* s04 = (const int4*)src0;
    const int4* d04 = (const int4*)dst0;
    const int4* s14 = (const int4*)src1;
    const int4* d14 = (const int4*)dst1;
    int lo = part * (N_DST0 / 8), hi = lo + (N_DST0 / 8);
    for (int i = bidx * 256 + threadIdx.x; i < E0 / 4; i += bpp * 256) {
      int4 d = d04[i]; int4 s = s04[i];
      if (d.x >= lo && d.x < hi) { int p = atomicAdd(&cnt0[d.x], 1); if (p < MAXDEG) eslot0[(size_t)d.x * MAXDEG + p] = s.x; }
      if (d.y >= lo && d.y < hi) { int p = atomicAdd(&cnt0[d.y], 1); if (p < MAXDEG) eslot0[(size_t)d.y * MAXDEG + p] = s.y; }
      if (d.z >= lo && d.z < hi) { int p = atomicAdd(&cnt0[d.z], 1); if (p < MAXDEG) eslot0[(size_t)d.z * MAXDEG + p] = s.z; }
      if (d.w >= lo && d.w < hi) { int p = atomicAdd(&cnt0[d.w], 1); if (p < MAXDEG) eslot0[(size_t)d.w * MAXDEG + p] = s.w; }
    }
    int lo1 = part * (N_DST1 / 8), hi1 = lo1 + (N_DST1 / 8);
    for (int i = bidx * 256 + threadIdx.x; i < E1 / 4; i += bpp * 256) {
      int4 d = d14[i]; int4 s = s14[i];
      if (d.x >= lo1 && d.x < hi1) { int p = atomicAdd(&cnt1[d.x], 1); if (p < MAXDEG) eslot1[(size_t)d.x * MAXDEG + p] = s.x; }
      if (d.y >= lo1 && d.y < hi1) { int p = atomicAdd(&cnt1[d.y], 1); if (p < MAXDEG) eslot1[(size_t)d.y * MAXDEG + p] = s.y; }
      if (d.z >= lo1 && d.z < hi1) { int p = atomicAdd(&cnt1[d.z], 1); if (p < MAXDEG) eslot1[(size_t)d.z * MAXDEG + p] = s.z; }
      if (d.w >= lo1 && d.w < hi1) { int p = atomicAdd(&cnt1[d.w], 1); if (p < MAXDEG) eslot1[(size_t)d.w * MAXDEG + p] = s.w; }
    }
    return;
  }

  // ---- fc role: one 16-row strip per wave, one-shot ----
  __shared__ uint16_t wl[16384];                  // 32 KB W fragments
  {
    const uint4* g = (const uint4*)Wf;
    uint4* sdst = (uint4*)wl;
    for (int i = threadIdx.x; i < 2048; i += 256) sdst[i] = g[i];
  }
  __syncthreads();

  const int lane = threadIdx.x & 63;
  const int q = lane >> 4, m16 = lane & 15;
  const int s = (blockIdx.x - PLACE_BLOCKS) * 4 + (threadIdx.x >> 6);
  if (s >= N_SRC0 / 16) return;

  const float* ap = feat + (size_t)(s * 16 + m16) * DIM + q * 8;
  float4 X[8];
#pragma unroll
  for (int kc = 0; kc < 4; kc++) {
    X[2 * kc]     = *(const float4*)(ap + kc * 32);
    X[2 * kc + 1] = *(const float4*)(ap + kc * 32 + 4);
  }

  float bv[8];
#pragma unroll
  for (int nt = 0; nt < 8; nt++) bv[nt] = bias[nt * 16 + m16];

  f32x4 acc[8];
#pragma unroll
  for (int nt = 0; nt < 8; nt++) acc[nt] = (f32x4){0.f, 0.f, 0.f, 0.f};

#pragma unroll
  for (int kc = 0; kc < 4; kc++) {
    float xs[8] = {X[2 * kc].x, X[2 * kc].y, X[2 * kc].z, X[2 * kc].w,
                   X[2 * kc + 1].x, X[2 * kc + 1].y, X[2 * kc + 1].z, X[2 * kc + 1].w};
    bf16x8 a;
#pragma unroll
    for (int j = 0; j < 8; j++) a[j] = (short)f2bf(xs[j]);
#pragma unroll
    for (int nt = 0; nt < 8; nt++) {
      bf16x8 wv = *(const bf16x8*)&wl[((kc * 8 + nt) * 64 + lane) * 8];
      acc[nt] = __builtin_amdgcn_mfma_f32_16x16x32_bf16(a, wv, acc[nt], 0, 0, 0);
    }
  }

  int m0 = s * 16;
#pragma unroll
  for (int nt = 0; nt < 8; nt++)
#pragma unroll
    for (int r = 0; r < 4; r++) {
      float v = fmaxf(acc[nt][r] + bv[nt], 0.f);
      hout[(size_t)(m0 + q * 4 + r) * DIM + nt * 16 + m16] = f2bf(v);
    }
}

// ---------------------------------------------------------------------------
// aggregate: wave per dst, one-shot. Lane owns 2 cols; mean -> bf16.
// ---------------------------------------------------------------------------
__global__ __launch_bounds__(256) void agg_kernel(
    const int* __restrict__ eslot, const int* __restrict__ deg,
    const uint16_t* __restrict__ hsrc, uint16_t* __restrict__ hout, int n_dst) {
  int d = (blockIdx.x * 256 + threadIdx.x) >> 6;
  int lane = threadIdx.x & 63;
  if (d >= n_dst) return;
  const int* sl = eslot + (size_t)d * MAXDEG;
  int dg = deg[d];
  int dgc = dg < MAXDEG ? dg : MAXDEG;
  float a0 = 0.f, a1 = 0.f;
  int e = 0;
  for (; e + 4 <= dgc; e += 4) {
    int s0 = sl[e], s1 = sl[e + 1], s2 = sl[e + 2], s3 = sl[e + 3];
    uint32_t p0 = *(const uint32_t*)(hsrc + (size_t)s0 * DIM + lane * 2);
    uint32_t p1 = *(const uint32_t*)(hsrc + (size_t)s1 * DIM + lane * 2);
    uint32_t p2 = *(const uint32_t*)(hsrc + (size_t)s2 * DIM + lane * 2);
    uint32_t p3 = *(const uint32_t*)(hsrc + (size_t)s3 * DIM + lane * 2);
    a0 += bf2f((uint16_t)p0) + bf2f((uint16_t)p1) + bf2f((uint16_t)p2) + bf2f((uint16_t)p3);
    a1 += bf2f((uint16_t)(p0 >> 16)) + bf2f((uint16_t)(p1 >> 16)) +
          bf2f((uint16_t)(p2 >> 16)) + bf2f((uint16_t)(p3 >> 16));
  }
  for (; e < dgc; e++) {
    uint32_t p = *(const uint32_t*)(hsrc + (size_t)sl[e] * DIM + lane * 2);
    a0 += bf2f((uint16_t)p);
    a1 += bf2f((uint16_t)(p >> 16));
  }
  float inv = 1.f / fmaxf((float)dg, 1.f);
  uint32_t o = (uint32_t)f2bf(a0 * inv) | ((uint32_t)f2bf(a1 * inv) << 16);
  *(uint32_t*)(hout + (size_t)d * DIM + lane * 2) = o;
}

// ---------------------------------------------------------------------------
// sage: one strip per wave one-shot; both W planes in LDS (64 KB).
// ---------------------------------------------------------------------------
template <bool ACT, bool OUT_BF16>
__global__ __launch_bounds__(256) void sage_kernel(
    const uint16_t* __restrict__ hself, const uint16_t* __restrict__ hneigh,
    const uint16_t* __restrict__ WfS, const uint16_t* __restrict__ WfN,
    const float* __restrict__ bS, const float* __restrict__ bN,
    void* __restrict__ outp, int n_dst) {
  __shared__ uint16_t wS[16384];
  __shared__ uint16_t wN[16384];
  {
    const uint4* gS = (const uint4*)WfS;
    const uint4* gN = (const uint4*)WfN;
    uint4* sS = (uint4*)wS;
    uint4* sN = (uint4*)wN;
    for (int i = threadIdx.x; i < 2048; i += 256) { sS[i] = gS[i]; sN[i] = gN[i]; }
  }
  __syncthreads();

  const int lane = threadIdx.x & 63;
  const int q = lane >> 4, m16 = lane & 15;
  const int s = blockIdx.x * 4 + (threadIdx.x >> 6);
  if (s >= n_dst / 16) return;

  size_t ro = (size_t)(s * 16 + m16) * DIM + q * 8;
  bf16x8 XS[4], XN[4];
#pragma unroll
  for (int kc = 0; kc < 4; kc++) {
    XS[kc] = *(const bf16x8*)(hself + ro + kc * 32);
    XN[kc] = *(const bf16x8*)(hneigh + ro + kc * 32);
  }

  float bv[8];
#pragma unroll
  for (int nt = 0; nt < 8; nt++)
    bv[nt] = bS[nt * 16 + m16] + bN[nt * 16 + m16];

  f32x4 acc[8];
#pragma unroll
  for (int nt = 0; nt < 8; nt++) acc[nt] = (f32x4){0.f, 0.f, 0.f, 0.f};

#pragma unroll
  for (int kc = 0; kc < 4; kc++) {
#pragma unroll
    for (int nt = 0; nt < 8; nt++) {
      size_t fo = (size_t)((kc * 8 + nt) * 64 + lane) * 8;
      bf16x8 ws = *(const bf16x8*)&wS[fo];
      bf16x8 wn = *(const bf16x8*)&wN[fo];
      acc[nt] = __builtin_amdgcn_mfma_f32_16x16x32_bf16(XS[kc], ws, acc[nt], 0, 0, 0);
      acc[nt] = __builtin_amdgcn_mfma_f32_16x16x32_bf16(XN[kc], wn, acc[nt], 0, 0, 0);
    }
  }

  int m0 = s * 16;
#pragma unroll
  for (int nt = 0; nt < 8; nt++)
#pragma unroll
    for (int r = 0; r < 4; r++) {
      float v = acc[nt][r] + bv[nt];
      if (ACT) v = fmaxf(v, 0.f);
      size_t o = (size_t)(m0 + q * 4 + r) * DIM + nt * 16 + m16;
      if (OUT_BF16) ((uint16_t*)outp)[o] = f2bf(v);
      else          ((float*)outp)[o] = v;
    }
}

// ---------------------------------------------------------------------------
// Workspace layout (bytes), total ~92.7 MB (ws_size ~409.6 MB):
//   h      @ 0           200000*128 bf16 = 51,200,000
//   h1     @ 51,200,000   50000*128 bf16 = 12,800,000
//   cnt0   @ 64,000,000   50000 int      =    200,000
//   cnt1   @ 64,200,000   10000 int      =     40,000
//   eslot0 @ 64,240,000   50000*64 int   = 12,800,000
//   eslot1 @ 77,040,000   10000*64 int   =  2,560,000
//   hn     @ 79,600,000   50000*128 bf16 = 12,800,000
//   Wf     @ 92,400,000   3*16384 bf16   =     98,304
// ---------------------------------------------------------------------------
extern "C" void kernel_launch(void* const* d_in, const int* in_sizes, int n_in,
                              void* d_out, int out_size, void* d_ws, size_t ws_size,
                              hipStream_t stream) {
  const float* feat   = (const float*)d_in[0];
  const int* src0     = (const int*)d_in[1];
  const int* dst0     = (const int*)d_in[2];
  const int* src1     = (const int*)d_in[3];
  const int* dst1     = (const int*)d_in[4];
  const float* W_init = (const float*)d_in[5];
  const float* b_init = (const float*)d_in[6];
  const float* W_self = (const float*)d_in[7];
  const float* b_self = (const float*)d_in[8];
  const float* W_neigh= (const float*)d_in[9];
  const float* b_neigh= (const float*)d_in[10];

  char* ws = (char*)d_ws;
  uint16_t* h     = (uint16_t*)(ws + 0);
  uint16_t* h1    = (uint16_t*)(ws + 51200000);
  int*      cnt0  = (int*)(ws + 64000000);
  int*      cnt1  = (int*)(ws + 64200000);
  int*      eslot0= (int*)(ws + 64240000);
  int*      eslot1= (int*)(ws + 77040000);
  uint16_t* hn    = (uint16_t*)(ws + 79600000);
  uint16_t* WfI   = (uint16_t*)(ws + 92400000);
  uint16_t* WfS   = WfI + 16384;
  uint16_t* WfN   = WfS + 16384;

  // 1: Wf frags + zero cnt0/cnt1 (contiguous 60000 ints)
  setup_kernel<<<214, 512, 0, stream>>>(W_init, W_self, W_neigh, WfI, cnt0, 60000);

  // 2: place (blocks 0-255) || fc one-shot strips (blocks 256..3380)
  fcplace_kernel<<<PLACE_BLOCKS + 3125, 256, 0, stream>>>(
      feat, WfI, b_init, h, src0, dst0, src1, dst1,
      cnt0, cnt1, eslot0, eslot1);

  // 3-4: layer 0
  agg_kernel<<<12500, 256, 0, stream>>>(eslot0, cnt0, h, hn, N_DST0);
  sage_kernel<true, true><<<782, 256, 0, stream>>>(h, hn, WfS, WfN,
                                                   b_self, b_neigh, h1, N_DST0);

  // 5-6: layer 1
  agg_kernel<<<2500, 256, 0, stream>>>(eslot1, cnt1, h1, hn, N_DST1);
  sage_kernel<false, false><<<157, 256, 0, stream>>>(h1, hn, WfS, WfN,
                                                     b_self, b_neigh, d_out, N_DST1);
}